// Round 13
// baseline (544.337 us; speedup 1.0000x reference)
//
#include <hip/hip_runtime.h>
#include <hip/hip_bf16.h>
#include <stdint.h>

#define BATCH 4
#define NPTS 50000
#define MTOT (BATCH * NPTS)   // 200000 points
#define HID 256
#define NBLK 5
#define CDIM 128

typedef float  floatx4 __attribute__((ext_vector_type(4)));
typedef short  short8  __attribute__((ext_vector_type(8)));

// ---- workspace layout (bytes) ----
#define OFF_WCP   0u           // 5*4*16*512 bf16  = 327,680 B
#define OFF_W0P   327680u      // 5*8*16*512 bf16  = 655,360 B
#define OFF_W1P   983040u      // 655,360 B
#define OFF_GT    1638400u     // 4*32768*32 bf16  = 8,388,608 B
#define OFF_PT    10027008u    // 3*4*16384*32 bf16 = 12,582,912 B  (end 22,609,920)

__device__ __forceinline__ unsigned short f2bf(float f) {
  unsigned u = __builtin_bit_cast(unsigned, f);
  u += 0x7fffu + ((u >> 16) & 1u);
  return (unsigned short)(u >> 16);
}
__device__ __forceinline__ unsigned pack2bf(float a, float b) {
  return (unsigned)f2bf(a) | ((unsigned)f2bf(b) << 16);
}
// packed cvt: lowers to v_cvt_pk_bf16_f32 on gfx950; RNE, value-identical to f2bf
__device__ __forceinline__ unsigned pk2(float a, float b) {
  __hip_bfloat162 t = __float22bfloat162_rn(make_float2(a, b));
  unsigned u; __builtin_memcpy(&u, &t, sizeof(u));
  return u;
}

// ---------------- prep: weight prepack + feature transpose (one launch) ----------------
// pack: fp32 row-major (K x 256) -> bf16 16x16x32 A-fragment-major.
// Fragment tile (ks, fm): 512 bf16, entry [l*8+j] = W[ks*32 + (l>>4)*8 + j][fm*16 + (l&15)]
__global__ void prep(const float* __restrict__ Wc, const float* __restrict__ W0,
                     const float* __restrict__ W1,
                     const float* __restrict__ g, const float* __restrict__ xy,
                     const float* __restrict__ yz, const float* __restrict__ xz,
                     unsigned short* __restrict__ wcp, unsigned short* __restrict__ w0p,
                     unsigned short* __restrict__ w1p,
                     unsigned short* __restrict__ gt, unsigned short* __restrict__ pt) {
  const int bid = blockIdx.x;
  if (bid < 3200) {
    // ---- weight pack: 819,200 elements ----
    int e = bid * 256 + threadIdx.x;
    const int WC_E = NBLK * 32768;   // 163840
    const int W_E  = NBLK * 65536;   // 327680
    const float* src;
    unsigned short* dst;
    int idx, per;
    if (e < WC_E)            { src = Wc; dst = wcp; idx = e;              per = 32768; }
    else if (e < WC_E + W_E) { src = W0; dst = w0p; idx = e - WC_E;       per = 65536; }
    else                     { src = W1; dst = w1p; idx = e - WC_E - W_E; per = 65536; }
    int blk = idx / per, r = idx % per;
    int j = r & 7, l = (r >> 3) & 63, tile = r >> 9;
    int fm = tile & 15, ks = tile >> 4;
    int k = ks * 32 + (l >> 4) * 8 + j;
    int n = fm * 16 + (l & 15);
    dst[idx] = f2bf(src[(size_t)blk * per + (size_t)k * 256 + n]);
    return;
  }
  // ---- feature transpose to channel-last bf16: 327,680 threads ----
  int tid = (bid - 3200) * 256 + threadIdx.x;
  float v[32];
  unsigned short* dst;
  if (tid < BATCH * 32768) {                 // grid: (B,32,32768) -> (B,32768,32)
    int b = tid >> 15, sp = tid & 32767;
    const float* src = g + ((size_t)b * 32) * 32768 + sp;
#pragma unroll
    for (int c = 0; c < 32; c++) v[c] = src[(size_t)c * 32768];
    dst = gt + (size_t)tid * 32;
  } else {                                   // planes: (3,B,32,16384) -> (3,B,16384,32)
    int t2 = tid - BATCH * 32768;
    int pl = t2 >> 16, rem = t2 & 65535;
    int b = rem >> 14, hw = rem & 16383;
    const float* pp = (pl == 0) ? xy : ((pl == 1) ? yz : xz);
    const float* src = pp + ((size_t)b * 32) * 16384 + hw;
#pragma unroll
    for (int c = 0; c < 32; c++) v[c] = src[(size_t)c * 16384];
    dst = pt + (size_t)t2 * 32;
  }
  uint4* d4 = (uint4*)dst;
#pragma unroll
  for (int i = 0; i < 4; i++) {
    uint4 u;
    u.x = pack2bf(v[i*8+0], v[i*8+1]);
    u.y = pack2bf(v[i*8+2], v[i*8+3]);
    u.z = pack2bf(v[i*8+4], v[i*8+5]);
    u.w = pack2bf(v[i*8+6], v[i*8+7]);
    d4[i] = u;
  }
}

// ---------------- interpolation helpers ----------
__device__ __forceinline__ void acc32(float* acc, const unsigned short* s, float w) {
  const uint4* q = (const uint4*)s;
#pragma unroll
  for (int i = 0; i < 4; i++) {
    uint4 u = q[i];
    acc[i*8+0] += w * __builtin_bit_cast(float, u.x << 16);
    acc[i*8+1] += w * __builtin_bit_cast(float, u.x & 0xffff0000u);
    acc[i*8+2] += w * __builtin_bit_cast(float, u.y << 16);
    acc[i*8+3] += w * __builtin_bit_cast(float, u.y & 0xffff0000u);
    acc[i*8+4] += w * __builtin_bit_cast(float, u.z << 16);
    acc[i*8+5] += w * __builtin_bit_cast(float, u.z & 0xffff0000u);
    acc[i*8+6] += w * __builtin_bit_cast(float, u.w << 16);
    acc[i*8+7] += w * __builtin_bit_cast(float, u.w & 0xffff0000u);
  }
}

// ---------------- fused gather + MLP ----------------
// R13 = resubmit of R10/R11/R12 (four GPU acquisition timeouts; kernel never ran).
// R10: register-tier break. R9 proved LDS reduction alone does NOT raise occupancy ->
// the binder is registers: 112 arch + 128 AGPR (net 64 + h 64) = 240/wave -> 512/240
// = 2 waves/SIMD. Fix: halve the point tile (fn=2, 32 points/block):
//   net[4][2] = 32 AGPR, h[4][2] = 32 AGPR (S2 stays UNSPLIT), arch ~95
//   => ~160 total <= 170 => 3 waves/SIMD (12 waves/CU, +50% TLP).
// Structure = R5's proven 2-barrier act/act2 ping-pong. LDS = act 32x512 + act2
// 32x512 + cf 32x256 = 40,960 B (obuf overlays cf) -> LDS never binds (3x40KB=120KB).
// Cost: weight L2 traffic doubles (6250 blocks x 1.6 MB = 10 GB ~ 29 TB/s) - under
// the 34.5 TB/s L2 ceiling. Arithmetic per point identical -> same absmax.
__global__ __launch_bounds__(256, 3) void mlp(
    const float* __restrict__ p, const float* __restrict__ Wp, const float* __restrict__ bp,
    const float* __restrict__ bc, const float* __restrict__ b0, const float* __restrict__ b1,
    const float* __restrict__ Wout, const float* __restrict__ bout,
    const unsigned short* __restrict__ wcp, const unsigned short* __restrict__ w0p,
    const unsigned short* __restrict__ w1p,
    const unsigned short* __restrict__ gt, const unsigned short* __restrict__ ptab,
    float* __restrict__ out) {
  __shared__ __align__(16) char smem[40960];   // act 32x512 + act2 32x512 + cf 32x256
  char* actB  = smem;                 // 32 rows x 512 B (swizzled)
  char* act2B = smem + 16384;         // 32 rows x 512 B (swizzled)
  char* cfLds = smem + 32768;         // 32 rows x 256 B (swizzled)
  float* obuf = (float*)(smem + 32768);  // overlays cf; cf reads all precede epilogue sync

  const int tid = threadIdx.x;
  const int w = tid >> 6, l = tid & 63, lq = l >> 4, lr = l & 15;
  const int rxl = (l & 7) << 4;           // swizzle term for row = *16 + lr accesses
  const int ptile = blockIdx.x * 32;

  // ---- gather prologue: 4 threads per point (128 threads active); stage into cf ----
  if (tid < 128) {
    int pl   = tid & 3;        // 0: grid, 1: xy, 2: yz, 3: xz
    int mloc = tid >> 2;       // 0..31
    int m = ptile + mloc;
    int b = m / NPTS;
    float px = p[3*m], py = p[3*m+1], pz = p[3*m+2];
    const float inv = 1.0f / 1.101f;       // 1/(1+PAD+1e-3)
    float ux = fminf(fmaxf(px * inv + 0.5f, 0.0f), 1.0f - 1e-5f);
    float uy = fminf(fmaxf(py * inv + 0.5f, 0.0f), 1.0f - 1e-5f);
    float uz = fminf(fmaxf(pz * inv + 0.5f, 0.0f), 1.0f - 1e-5f);
    float acc[32];
#pragma unroll
    for (int c = 0; c < 32; c++) acc[c] = 0.f;
    if (pl == 0) {
      // trilinear grid (x->W fastest), res 32
      float fx = ux * 31.f, fy = uy * 31.f, fz = uz * 31.f;
      int x0 = (int)fx, y0 = (int)fy, z0 = (int)fz;
      float wx = fx - x0, wy = fy - y0, wz = fz - z0;
      int x1 = min(x0 + 1, 31), y1 = min(y0 + 1, 31), z1 = min(z0 + 1, 31);
      const unsigned short* gb = gt + ((size_t)b * 32768) * 32;
      #define GI(z,y,x) (((size_t)(((z)*32 + (y))*32 + (x))) * 32)
      acc32(acc, gb + GI(z0,y0,x0), (1-wx)*(1-wy)*(1-wz));
      acc32(acc, gb + GI(z0,y0,x1), wx*(1-wy)*(1-wz));
      acc32(acc, gb + GI(z0,y1,x0), (1-wx)*wy*(1-wz));
      acc32(acc, gb + GI(z0,y1,x1), wx*wy*(1-wz));
      acc32(acc, gb + GI(z1,y0,x0), (1-wx)*(1-wy)*wz);
      acc32(acc, gb + GI(z1,y0,x1), wx*(1-wy)*wz);
      acc32(acc, gb + GI(z1,y1,x0), (1-wx)*wy*wz);
      acc32(acc, gb + GI(z1,y1,x1), wx*wy*wz);
    } else {
      // bilinear plane, res 128: xy(u=x,v=y), yz(u=y,v=z), xz(u=x,v=z)
      float uu = (pl == 2) ? uy : ux;
      float vv = (pl == 1) ? uy : uz;
      float fx = uu * 127.f, fy = vv * 127.f;
      int x0 = (int)fx, y0 = (int)fy;
      float wx = fx - x0, wy = fy - y0;
      int x1 = min(x0 + 1, 127), y1 = min(y0 + 1, 127);
      const unsigned short* pb = ptab + ((size_t)((pl - 1) * BATCH + b) * 16384) * 32;
      acc32(acc, pb + ((size_t)(y0*128 + x0)) * 32, (1-wx)*(1-wy));
      acc32(acc, pb + ((size_t)(y0*128 + x1)) * 32, wx*(1-wy));
      acc32(acc, pb + ((size_t)(y1*128 + x0)) * 32, (1-wx)*wy);
      acc32(acc, pb + ((size_t)(y1*128 + x1)) * 32, wx*wy);
    }
    // store 32 channels (bf16) to cf row mloc, byte cols pl*64 + i*16, swizzled
    int rxm = (mloc & 7) << 4;
    char* rowp = cfLds + mloc * 256;
#pragma unroll
    for (int i = 0; i < 4; i++) {
      uint4 u;
      u.x = pack2bf(acc[i*8+0], acc[i*8+1]);
      u.y = pack2bf(acc[i*8+2], acc[i*8+3]);
      u.z = pack2bf(acc[i*8+4], acc[i*8+5]);
      u.w = pack2bf(acc[i*8+6], acc[i*8+7]);
      *(uint4*)(rowp + ((pl*64 + i*16) ^ rxm)) = u;
    }
  }

  floatx4 net[4][2];   // [fm][fn]; hidden = w*64 + fm*16 + lq*4 + r ; point = fn*16 + lr

  // ---- init: net = p @ Wp + bp ----
  float pv[2][3];
#pragma unroll
  for (int fn = 0; fn < 2; fn++) {
    int pg = ptile + fn * 16 + lr;
    pv[fn][0] = p[pg*3]; pv[fn][1] = p[pg*3+1]; pv[fn][2] = p[pg*3+2];
  }
#pragma unroll
  for (int fm = 0; fm < 4; fm++) {
    int h4 = w*16 + fm*4 + lq;
    float4 w0q = ((const float4*)Wp)[h4];
    float4 w1q = ((const float4*)(Wp + 256))[h4];
    float4 w2q = ((const float4*)(Wp + 512))[h4];
    float4 bq  = ((const float4*)bp)[h4];
    float wq[4][3] = {{w0q.x,w1q.x,w2q.x},{w0q.y,w1q.y,w2q.y},
                      {w0q.z,w1q.z,w2q.z},{w0q.w,w1q.w,w2q.w}};
    float bb[4] = {bq.x, bq.y, bq.z, bq.w};
#pragma unroll
    for (int r = 0; r < 4; r++)
#pragma unroll
      for (int fn = 0; fn < 2; fn++)
        net[fm][fn][r] = bb[r] + pv[fn][0]*wq[r][0] + pv[fn][1]*wq[r][1] + pv[fn][2]*wq[r][2];
  }
  __syncthreads();   // cf staging complete

  for (int i = 0; i < NBLK; i++) {
    // ---- S1: net += Wc^T . c^T  (K = 128; B-frags from cf LDS) ----
    const unsigned short* wcb = wcp + i * 32768;
#pragma unroll
    for (int ks = 0; ks < 4; ks++) {
      short8 af[4], bf[2];
#pragma unroll
      for (int fm = 0; fm < 4; fm++)
        af[fm] = *(const short8*)(wcb + (size_t)(ks*16 + w*4 + fm) * 512 + l*8);
#pragma unroll
      for (int fn = 0; fn < 2; fn++)
        bf[fn] = *(const short8*)(cfLds + (fn*16 + lr) * 256 + ((ks*64 + lq*16) ^ rxl));
      __builtin_amdgcn_s_setprio(1);
#pragma unroll
      for (int fm = 0; fm < 4; fm++)
#pragma unroll
        for (int fn = 0; fn < 2; fn++)
          net[fm][fn] = __builtin_amdgcn_mfma_f32_16x16x32_bf16(af[fm], bf[fn], net[fm][fn], 0, 0, 0);
      __builtin_amdgcn_s_setprio(0);
    }
    // ---- + bc, stage relu(net) -> act  (prev iter's S2 act-reads fenced by prev B2) ----
#pragma unroll
    for (int fm = 0; fm < 4; fm++) {
      float4 bq = ((const float4*)(bc + i*256))[w*16 + fm*4 + lq];
      float bb[4] = {bq.x, bq.y, bq.z, bq.w};
#pragma unroll
      for (int fn = 0; fn < 2; fn++) {
#pragma unroll
        for (int r = 0; r < 4; r++) net[fm][fn][r] += bb[r];
        uint2 uu;
        uu.x = pk2(fmaxf(net[fm][fn][0],0.f), fmaxf(net[fm][fn][1],0.f));
        uu.y = pk2(fmaxf(net[fm][fn][2],0.f), fmaxf(net[fm][fn][3],0.f));
        *(uint2*)(actB + (fn*16 + lr) * 512 + ((w*128 + fm*32 + lq*8) ^ rxl)) = uu;
      }
    }
    __syncthreads();   // B1: act complete; also fences last iter's act2 reads
    // ---- S2: h = W0^T . relu(net)^T  (K = 256), UNSPLIT; write relu(h) -> act2 ----
    const unsigned short* w0b = w0p + i * 65536;
    floatx4 h[4][2];
#pragma unroll
    for (int fm = 0; fm < 4; fm++)
#pragma unroll
      for (int fn = 0; fn < 2; fn++) h[fm][fn] = (floatx4){0.f,0.f,0.f,0.f};
#pragma unroll
    for (int ks = 0; ks < 8; ks++) {
      short8 af[4], bf[2];
#pragma unroll
      for (int fm = 0; fm < 4; fm++)
        af[fm] = *(const short8*)(w0b + (size_t)(ks*16 + w*4 + fm) * 512 + l*8);
#pragma unroll
      for (int fn = 0; fn < 2; fn++)
        bf[fn] = *(const short8*)(actB + (fn*16 + lr) * 512 + ((ks*64 + lq*16) ^ rxl));
      __builtin_amdgcn_s_setprio(1);
#pragma unroll
      for (int fm = 0; fm < 4; fm++)
#pragma unroll
        for (int fn = 0; fn < 2; fn++)
          h[fm][fn] = __builtin_amdgcn_mfma_f32_16x16x32_bf16(af[fm], bf[fn], h[fm][fn], 0, 0, 0);
      __builtin_amdgcn_s_setprio(0);
    }
#pragma unroll
    for (int fm = 0; fm < 4; fm++) {
      float4 bq = ((const float4*)(b0 + i*256))[w*16 + fm*4 + lq];
      float bb[4] = {bq.x, bq.y, bq.z, bq.w};
#pragma unroll
      for (int fn = 0; fn < 2; fn++) {
        uint2 uu;
        uu.x = pk2(fmaxf(h[fm][fn][0]+bb[0],0.f), fmaxf(h[fm][fn][1]+bb[1],0.f));
        uu.y = pk2(fmaxf(h[fm][fn][2]+bb[2],0.f), fmaxf(h[fm][fn][3]+bb[3],0.f));
        *(uint2*)(act2B + (fn*16 + lr) * 512 + ((w*128 + fm*32 + lq*8) ^ rxl)) = uu;
      }
    }
    __syncthreads();   // B2: act2 complete; also fences this iter's act reads
    // ---- S3: net += W1^T . relu(h)^T + b1 ----
    const unsigned short* w1b = w1p + i * 65536;
#pragma unroll
    for (int ks = 0; ks < 8; ks++) {
      short8 af[4], bf[2];
#pragma unroll
      for (int fm = 0; fm < 4; fm++)
        af[fm] = *(const short8*)(w1b + (size_t)(ks*16 + w*4 + fm) * 512 + l*8);
#pragma unroll
      for (int fn = 0; fn < 2; fn++)
        bf[fn] = *(const short8*)(act2B + (fn*16 + lr) * 512 + ((ks*64 + lq*16) ^ rxl));
      __builtin_amdgcn_s_setprio(1);
#pragma unroll
      for (int fm = 0; fm < 4; fm++)
#pragma unroll
        for (int fn = 0; fn < 2; fn++)
          net[fm][fn] = __builtin_amdgcn_mfma_f32_16x16x32_bf16(af[fm], bf[fn], net[fm][fn], 0, 0, 0);
      __builtin_amdgcn_s_setprio(0);
    }
#pragma unroll
    for (int fm = 0; fm < 4; fm++) {
      float4 bq = ((const float4*)(b1 + i*256))[w*16 + fm*4 + lq];
      float bb[4] = {bq.x, bq.y, bq.z, bq.w};
#pragma unroll
      for (int r = 0; r < 4; r++)
#pragma unroll
        for (int fn = 0; fn < 2; fn++) net[fm][fn][r] += bb[r];
    }
  }

  // ---- out = relu(net) @ Wout + bout  (obuf overlays cf; cf reads ended before last B1) ----
  float s[2] = {0.f, 0.f};
#pragma unroll
  for (int fm = 0; fm < 4; fm++) {
    float4 wq = ((const float4*)Wout)[w*16 + fm*4 + lq];
    float wv[4] = {wq.x, wq.y, wq.z, wq.w};
#pragma unroll
    for (int r = 0; r < 4; r++)
#pragma unroll
      for (int fn = 0; fn < 2; fn++) s[fn] += fmaxf(net[fm][fn][r], 0.f) * wv[r];
  }
#pragma unroll
  for (int fn = 0; fn < 2; fn++) {
    s[fn] += __shfl_xor(s[fn], 16);
    s[fn] += __shfl_xor(s[fn], 32);
  }
  if (tid < 32) obuf[tid] = 0.f;
  __syncthreads();
  if (lq == 0) {
#pragma unroll
    for (int fn = 0; fn < 2; fn++) atomicAdd(&obuf[fn*16 + lr], s[fn]);
  }
  __syncthreads();
  if (tid < 32) out[ptile + tid] = obuf[tid] + bout[0];
}

extern "C" void kernel_launch(void* const* d_in, const int* in_sizes, int n_in,
                              void* d_out, int out_size, void* d_ws, size_t ws_size,
                              hipStream_t stream) {
  const float* p      = (const float*)d_in[0];
  const float* c_grid = (const float*)d_in[1];
  const float* c_xy   = (const float*)d_in[2];
  const float* c_yz   = (const float*)d_in[3];
  const float* c_xz   = (const float*)d_in[4];
  const float* Wp     = (const float*)d_in[5];
  const float* bp     = (const float*)d_in[6];
  const float* Wc     = (const float*)d_in[7];
  const float* bc     = (const float*)d_in[8];
  const float* W0     = (const float*)d_in[9];
  const float* b0     = (const float*)d_in[10];
  const float* W1     = (const float*)d_in[11];
  const float* b1     = (const float*)d_in[12];
  const float* Wout   = (const float*)d_in[13];
  const float* bout   = (const float*)d_in[14];

  char* ws = (char*)d_ws;
  unsigned short* wcp = (unsigned short*)(ws + OFF_WCP);
  unsigned short* w0p = (unsigned short*)(ws + OFF_W0P);
  unsigned short* w1p = (unsigned short*)(ws + OFF_W1P);
  unsigned short* gt  = (unsigned short*)(ws + OFF_GT);
  unsigned short* pt  = (unsigned short*)(ws + OFF_PT);
  float* out = (float*)d_out;

  prep<<<4480, 256, 0, stream>>>(Wc, W0, W1, c_grid, c_xy, c_yz, c_xz,
                                 wcp, w0p, w1p, gt, pt);
  mlp<<<MTOT / 32, 256, 0, stream>>>(p, Wp, bp, bc, b0, b1, Wout, bout,
                                     wcp, w0p, w1p, gt, pt, out);
}

// Round 15
// 493.659 us; speedup vs baseline: 1.1027x; 1.1027x over previous
//
#include <hip/hip_runtime.h>
#include <hip/hip_bf16.h>
#include <stdint.h>

#define BATCH 4
#define NPTS 50000
#define MTOT (BATCH * NPTS)   // 200000 points
#define HID 256
#define NBLK 5
#define CDIM 128

typedef float  floatx4 __attribute__((ext_vector_type(4)));
typedef short  short8  __attribute__((ext_vector_type(8)));

// ---- workspace layout (bytes) ----
#define OFF_WCP   0u           // 5*4*16*512 bf16  = 327,680 B
#define OFF_W0P   327680u      // 5*8*16*512 bf16  = 655,360 B
#define OFF_W1P   983040u      // 655,360 B
#define OFF_GT    1638400u     // 4*32768*32 bf16  = 8,388,608 B
#define OFF_PT    10027008u    // 3*4*16384*32 bf16 = 12,582,912 B  (end 22,609,920)

__device__ __forceinline__ unsigned short f2bf(float f) {
  unsigned u = __builtin_bit_cast(unsigned, f);
  u += 0x7fffu + ((u >> 16) & 1u);
  return (unsigned short)(u >> 16);
}
__device__ __forceinline__ unsigned pack2bf(float a, float b) {
  return (unsigned)f2bf(a) | ((unsigned)f2bf(b) << 16);
}
// packed cvt: lowers to v_cvt_pk_bf16_f32 on gfx950; RNE, value-identical to f2bf
__device__ __forceinline__ unsigned pk2(float a, float b) {
  __hip_bfloat162 t = __float22bfloat162_rn(make_float2(a, b));
  unsigned u; __builtin_memcpy(&u, &t, sizeof(u));
  return u;
}

// ---------------- prep: weight prepack + feature transpose (one launch) ----------------
// pack: fp32 row-major (K x 256) -> bf16 16x16x32 A-fragment-major.
// Fragment tile (ks, fm): 512 bf16, entry [l*8+j] = W[ks*32 + (l>>4)*8 + j][fm*16 + (l&15)]
__global__ void prep(const float* __restrict__ Wc, const float* __restrict__ W0,
                     const float* __restrict__ W1,
                     const float* __restrict__ g, const float* __restrict__ xy,
                     const float* __restrict__ yz, const float* __restrict__ xz,
                     unsigned short* __restrict__ wcp, unsigned short* __restrict__ w0p,
                     unsigned short* __restrict__ w1p,
                     unsigned short* __restrict__ gt, unsigned short* __restrict__ pt) {
  const int bid = blockIdx.x;
  if (bid < 3200) {
    // ---- weight pack: 819,200 elements ----
    int e = bid * 256 + threadIdx.x;
    const int WC_E = NBLK * 32768;   // 163840
    const int W_E  = NBLK * 65536;   // 327680
    const float* src;
    unsigned short* dst;
    int idx, per;
    if (e < WC_E)            { src = Wc; dst = wcp; idx = e;              per = 32768; }
    else if (e < WC_E + W_E) { src = W0; dst = w0p; idx = e - WC_E;       per = 65536; }
    else                     { src = W1; dst = w1p; idx = e - WC_E - W_E; per = 65536; }
    int blk = idx / per, r = idx % per;
    int j = r & 7, l = (r >> 3) & 63, tile = r >> 9;
    int fm = tile & 15, ks = tile >> 4;
    int k = ks * 32 + (l >> 4) * 8 + j;
    int n = fm * 16 + (l & 15);
    dst[idx] = f2bf(src[(size_t)blk * per + (size_t)k * 256 + n]);
    return;
  }
  // ---- feature transpose to channel-last bf16: 327,680 threads ----
  int tid = (bid - 3200) * 256 + threadIdx.x;
  float v[32];
  unsigned short* dst;
  if (tid < BATCH * 32768) {                 // grid: (B,32,32768) -> (B,32768,32)
    int b = tid >> 15, sp = tid & 32767;
    const float* src = g + ((size_t)b * 32) * 32768 + sp;
#pragma unroll
    for (int c = 0; c < 32; c++) v[c] = src[(size_t)c * 32768];
    dst = gt + (size_t)tid * 32;
  } else {                                   // planes: (3,B,32,16384) -> (3,B,16384,32)
    int t2 = tid - BATCH * 32768;
    int pl = t2 >> 16, rem = t2 & 65535;
    int b = rem >> 14, hw = rem & 16383;
    const float* pp = (pl == 0) ? xy : ((pl == 1) ? yz : xz);
    const float* src = pp + ((size_t)b * 32) * 16384 + hw;
#pragma unroll
    for (int c = 0; c < 32; c++) v[c] = src[(size_t)c * 16384];
    dst = pt + (size_t)t2 * 32;
  }
  uint4* d4 = (uint4*)dst;
#pragma unroll
  for (int i = 0; i < 4; i++) {
    uint4 u;
    u.x = pack2bf(v[i*8+0], v[i*8+1]);
    u.y = pack2bf(v[i*8+2], v[i*8+3]);
    u.z = pack2bf(v[i*8+4], v[i*8+5]);
    u.w = pack2bf(v[i*8+6], v[i*8+7]);
    d4[i] = u;
  }
}

// ---------------- interpolation helpers ----------
__device__ __forceinline__ void acc32(float* acc, const unsigned short* s, float w) {
  const uint4* q = (const uint4*)s;
#pragma unroll
  for (int i = 0; i < 4; i++) {
    uint4 u = q[i];
    acc[i*8+0] += w * __builtin_bit_cast(float, u.x << 16);
    acc[i*8+1] += w * __builtin_bit_cast(float, u.x & 0xffff0000u);
    acc[i*8+2] += w * __builtin_bit_cast(float, u.y << 16);
    acc[i*8+3] += w * __builtin_bit_cast(float, u.y & 0xffff0000u);
    acc[i*8+4] += w * __builtin_bit_cast(float, u.z << 16);
    acc[i*8+5] += w * __builtin_bit_cast(float, u.z & 0xffff0000u);
    acc[i*8+6] += w * __builtin_bit_cast(float, u.w << 16);
    acc[i*8+7] += w * __builtin_bit_cast(float, u.w & 0xffff0000u);
  }
}

// ---------------- fused gather + MLP ----------------
// R15 = byte-identical resubmit of R5 (verified best: 492.7 us total / 417.5 us mlp,
// absmax 0.0314). Session evidence closed the search space:
//  - R9: occupancy is register-bound (240/wave), not LDS-bound.
//  - R13: raising occupancy via fn=2 regressed (weight-load:MFMA ratio doubled).
//  - R3: barrier-free wave-local form loses 3x on L2 weight traffic.
//  - R2: S2 splits lose; R1-despill via cf-in-LDS (this kernel) won.
//  - R8/R14: two arithmetically-identical transforms with barrier-adjacent load
//    motion failed correctness inexplicably -> that direction is off-limits.
// Structure: 4 waves x 64 hidden, 64 points, 2-barrier act/act2 ping-pong, UNSPLIT S2;
// cf in dedicated swizzled LDS; act 64x512 + act2 64x512 + cf 64x256 = 81,920 B
// -> 2 blocks/CU; obuf overlays cf (dead by epilogue).
__global__ __launch_bounds__(256, 2) void mlp(
    const float* __restrict__ p, const float* __restrict__ Wp, const float* __restrict__ bp,
    const float* __restrict__ bc, const float* __restrict__ b0, const float* __restrict__ b1,
    const float* __restrict__ Wout, const float* __restrict__ bout,
    const unsigned short* __restrict__ wcp, const unsigned short* __restrict__ w0p,
    const unsigned short* __restrict__ w1p,
    const unsigned short* __restrict__ gt, const unsigned short* __restrict__ ptab,
    float* __restrict__ out) {
  __shared__ __align__(16) unsigned short smem[40960];   // 81,920 B exact
  char* actB  = (char*)smem;              // 64 rows x 512 B (swizzled)
  char* act2B = (char*)smem + 32768;      // 64 rows x 512 B (swizzled)
  char* cfLds = (char*)smem + 65536;      // 64 rows x 256 B (swizzled)
  float* obuf = (float*)((char*)smem + 65536);  // overlays cf; dead region at epilogue

  const int tid = threadIdx.x;
  const int w = tid >> 6, l = tid & 63, lq = l >> 4, lr = l & 15;
  const int rxl = (l & 7) << 4;           // swizzle term for row = *16 + lr accesses
  const int ptile = blockIdx.x * 64;

  // ---- gather prologue: 4 threads per point, one feature source each; stage into cf ----
  {
    int pl   = tid & 3;        // 0: grid, 1: xy, 2: yz, 3: xz
    int mloc = tid >> 2;       // 0..63
    int m = ptile + mloc;
    int b = m / NPTS;
    float px = p[3*m], py = p[3*m+1], pz = p[3*m+2];
    const float inv = 1.0f / 1.101f;       // 1/(1+PAD+1e-3)
    float ux = fminf(fmaxf(px * inv + 0.5f, 0.0f), 1.0f - 1e-5f);
    float uy = fminf(fmaxf(py * inv + 0.5f, 0.0f), 1.0f - 1e-5f);
    float uz = fminf(fmaxf(pz * inv + 0.5f, 0.0f), 1.0f - 1e-5f);
    float acc[32];
#pragma unroll
    for (int c = 0; c < 32; c++) acc[c] = 0.f;
    if (pl == 0) {
      // trilinear grid (x->W fastest), res 32
      float fx = ux * 31.f, fy = uy * 31.f, fz = uz * 31.f;
      int x0 = (int)fx, y0 = (int)fy, z0 = (int)fz;
      float wx = fx - x0, wy = fy - y0, wz = fz - z0;
      int x1 = min(x0 + 1, 31), y1 = min(y0 + 1, 31), z1 = min(z0 + 1, 31);
      const unsigned short* gb = gt + ((size_t)b * 32768) * 32;
      #define GI(z,y,x) (((size_t)(((z)*32 + (y))*32 + (x))) * 32)
      acc32(acc, gb + GI(z0,y0,x0), (1-wx)*(1-wy)*(1-wz));
      acc32(acc, gb + GI(z0,y0,x1), wx*(1-wy)*(1-wz));
      acc32(acc, gb + GI(z0,y1,x0), (1-wx)*wy*(1-wz));
      acc32(acc, gb + GI(z0,y1,x1), wx*wy*(1-wz));
      acc32(acc, gb + GI(z1,y0,x0), (1-wx)*(1-wy)*wz);
      acc32(acc, gb + GI(z1,y0,x1), wx*(1-wy)*wz);
      acc32(acc, gb + GI(z1,y1,x0), (1-wx)*wy*wz);
      acc32(acc, gb + GI(z1,y1,x1), wx*wy*wz);
    } else {
      // bilinear plane, res 128: xy(u=x,v=y), yz(u=y,v=z), xz(u=x,v=z)
      float uu = (pl == 2) ? uy : ux;
      float vv = (pl == 1) ? uy : uz;
      float fx = uu * 127.f, fy = vv * 127.f;
      int x0 = (int)fx, y0 = (int)fy;
      float wx = fx - x0, wy = fy - y0;
      int x1 = min(x0 + 1, 127), y1 = min(y0 + 1, 127);
      const unsigned short* pb = ptab + ((size_t)((pl - 1) * BATCH + b) * 16384) * 32;
      acc32(acc, pb + ((size_t)(y0*128 + x0)) * 32, (1-wx)*(1-wy));
      acc32(acc, pb + ((size_t)(y0*128 + x1)) * 32, wx*(1-wy));
      acc32(acc, pb + ((size_t)(y1*128 + x0)) * 32, (1-wx)*wy);
      acc32(acc, pb + ((size_t)(y1*128 + x1)) * 32, wx*wy);
    }
    // store 32 channels (bf16) to cf row mloc, byte cols pl*64 + i*16, swizzled
    int rxm = (mloc & 7) << 4;
    char* rowp = cfLds + mloc * 256;
#pragma unroll
    for (int i = 0; i < 4; i++) {
      uint4 u;
      u.x = pack2bf(acc[i*8+0], acc[i*8+1]);
      u.y = pack2bf(acc[i*8+2], acc[i*8+3]);
      u.z = pack2bf(acc[i*8+4], acc[i*8+5]);
      u.w = pack2bf(acc[i*8+6], acc[i*8+7]);
      *(uint4*)(rowp + ((pl*64 + i*16) ^ rxm)) = u;
    }
  }

  floatx4 net[4][4];   // [fm][fn]; hidden = w*64 + fm*16 + lq*4 + r ; point = fn*16 + lr

  // ---- init: net = p @ Wp + bp ----
  float pv[4][3];
#pragma unroll
  for (int fn = 0; fn < 4; fn++) {
    int pg = ptile + fn * 16 + lr;
    pv[fn][0] = p[pg*3]; pv[fn][1] = p[pg*3+1]; pv[fn][2] = p[pg*3+2];
  }
#pragma unroll
  for (int fm = 0; fm < 4; fm++) {
    int h4 = w*16 + fm*4 + lq;
    float4 w0q = ((const float4*)Wp)[h4];
    float4 w1q = ((const float4*)(Wp + 256))[h4];
    float4 w2q = ((const float4*)(Wp + 512))[h4];
    float4 bq  = ((const float4*)bp)[h4];
    float wq[4][3] = {{w0q.x,w1q.x,w2q.x},{w0q.y,w1q.y,w2q.y},
                      {w0q.z,w1q.z,w2q.z},{w0q.w,w1q.w,w2q.w}};
    float bb[4] = {bq.x, bq.y, bq.z, bq.w};
#pragma unroll
    for (int r = 0; r < 4; r++)
#pragma unroll
      for (int fn = 0; fn < 4; fn++)
        net[fm][fn][r] = bb[r] + pv[fn][0]*wq[r][0] + pv[fn][1]*wq[r][1] + pv[fn][2]*wq[r][2];
  }
  __syncthreads();   // cf staging complete (act/act2 untouched so far)

  for (int i = 0; i < NBLK; i++) {
    // ---- S1: net += Wc^T . c^T  (K = 128; B-frags re-read from cf LDS) ----
    const unsigned short* wcb = wcp + i * 32768;
#pragma unroll
    for (int ks = 0; ks < 4; ks++) {
      short8 af[4], bf[4];
#pragma unroll
      for (int fm = 0; fm < 4; fm++)
        af[fm] = *(const short8*)(wcb + (size_t)(ks*16 + w*4 + fm) * 512 + l*8);
#pragma unroll
      for (int fn = 0; fn < 4; fn++)
        bf[fn] = *(const short8*)(cfLds + (fn*16 + lr) * 256 + ((ks*64 + lq*16) ^ rxl));
      __builtin_amdgcn_s_setprio(1);
#pragma unroll
      for (int fm = 0; fm < 4; fm++)
#pragma unroll
        for (int fn = 0; fn < 4; fn++)
          net[fm][fn] = __builtin_amdgcn_mfma_f32_16x16x32_bf16(af[fm], bf[fn], net[fm][fn], 0, 0, 0);
      __builtin_amdgcn_s_setprio(0);
    }
    // ---- + bc, stage relu(net) -> act  (prev iter's S2 act-reads fenced by prev B2) ----
#pragma unroll
    for (int fm = 0; fm < 4; fm++) {
      float4 bq = ((const float4*)(bc + i*256))[w*16 + fm*4 + lq];
      float bb[4] = {bq.x, bq.y, bq.z, bq.w};
#pragma unroll
      for (int fn = 0; fn < 4; fn++) {
#pragma unroll
        for (int r = 0; r < 4; r++) net[fm][fn][r] += bb[r];
        uint2 uu;
        uu.x = pk2(fmaxf(net[fm][fn][0],0.f), fmaxf(net[fm][fn][1],0.f));
        uu.y = pk2(fmaxf(net[fm][fn][2],0.f), fmaxf(net[fm][fn][3],0.f));
        *(uint2*)(actB + (fn*16 + lr) * 512 + ((w*128 + fm*32 + lq*8) ^ rxl)) = uu;
      }
    }
    __syncthreads();   // B1: act complete; also fences last iter's act2 reads
    // ---- S2: h = W0^T . relu(net)^T  (K = 256), UNSPLIT; write relu(h) -> act2 ----
    const unsigned short* w0b = w0p + i * 65536;
    floatx4 h[4][4];
#pragma unroll
    for (int fm = 0; fm < 4; fm++)
#pragma unroll
      for (int fn = 0; fn < 4; fn++) h[fm][fn] = (floatx4){0.f,0.f,0.f,0.f};
#pragma unroll
    for (int ks = 0; ks < 8; ks++) {
      short8 af[4], bf[4];
#pragma unroll
      for (int fm = 0; fm < 4; fm++)
        af[fm] = *(const short8*)(w0b + (size_t)(ks*16 + w*4 + fm) * 512 + l*8);
#pragma unroll
      for (int fn = 0; fn < 4; fn++)
        bf[fn] = *(const short8*)(actB + (fn*16 + lr) * 512 + ((ks*64 + lq*16) ^ rxl));
      __builtin_amdgcn_s_setprio(1);
#pragma unroll
      for (int fm = 0; fm < 4; fm++)
#pragma unroll
        for (int fn = 0; fn < 4; fn++)
          h[fm][fn] = __builtin_amdgcn_mfma_f32_16x16x32_bf16(af[fm], bf[fn], h[fm][fn], 0, 0, 0);
      __builtin_amdgcn_s_setprio(0);
    }
#pragma unroll
    for (int fm = 0; fm < 4; fm++) {
      float4 bq = ((const float4*)(b0 + i*256))[w*16 + fm*4 + lq];
      float bb[4] = {bq.x, bq.y, bq.z, bq.w};
#pragma unroll
      for (int fn = 0; fn < 4; fn++) {
        uint2 uu;
        uu.x = pk2(fmaxf(h[fm][fn][0]+bb[0],0.f), fmaxf(h[fm][fn][1]+bb[1],0.f));
        uu.y = pk2(fmaxf(h[fm][fn][2]+bb[2],0.f), fmaxf(h[fm][fn][3]+bb[3],0.f));
        *(uint2*)(act2B + (fn*16 + lr) * 512 + ((w*128 + fm*32 + lq*8) ^ rxl)) = uu;
      }
    }
    __syncthreads();   // B2: act2 complete; also fences this iter's act reads
    // ---- S3: net += W1^T . relu(h)^T + b1 ----
    const unsigned short* w1b = w1p + i * 65536;
#pragma unroll
    for (int ks = 0; ks < 8; ks++) {
      short8 af[4], bf[4];
#pragma unroll
      for (int fm = 0; fm < 4; fm++)
        af[fm] = *(const short8*)(w1b + (size_t)(ks*16 + w*4 + fm) * 512 + l*8);
#pragma unroll
      for (int fn = 0; fn < 4; fn++)
        bf[fn] = *(const short8*)(act2B + (fn*16 + lr) * 512 + ((ks*64 + lq*16) ^ rxl));
      __builtin_amdgcn_s_setprio(1);
#pragma unroll
      for (int fm = 0; fm < 4; fm++)
#pragma unroll
        for (int fn = 0; fn < 4; fn++)
          net[fm][fn] = __builtin_amdgcn_mfma_f32_16x16x32_bf16(af[fm], bf[fn], net[fm][fn], 0, 0, 0);
      __builtin_amdgcn_s_setprio(0);
    }
#pragma unroll
    for (int fm = 0; fm < 4; fm++) {
      float4 bq = ((const float4*)(b1 + i*256))[w*16 + fm*4 + lq];
      float bb[4] = {bq.x, bq.y, bq.z, bq.w};
#pragma unroll
      for (int r = 0; r < 4; r++)
#pragma unroll
        for (int fn = 0; fn < 4; fn++) net[fm][fn][r] += bb[r];
    }
  }

  // ---- out = relu(net) @ Wout + bout  (obuf overlays cf: cf reads ended pre-B1 of last iter) ----
  float s[4] = {0.f, 0.f, 0.f, 0.f};
#pragma unroll
  for (int fm = 0; fm < 4; fm++) {
    float4 wq = ((const float4*)Wout)[w*16 + fm*4 + lq];
    float wv[4] = {wq.x, wq.y, wq.z, wq.w};
#pragma unroll
    for (int r = 0; r < 4; r++)
#pragma unroll
      for (int fn = 0; fn < 4; fn++) s[fn] += fmaxf(net[fm][fn][r], 0.f) * wv[r];
  }
#pragma unroll
  for (int fn = 0; fn < 4; fn++) {
    s[fn] += __shfl_xor(s[fn], 16);
    s[fn] += __shfl_xor(s[fn], 32);
  }
  if (tid < 64) obuf[tid] = 0.f;
  __syncthreads();
  if (lq == 0) {
#pragma unroll
    for (int fn = 0; fn < 4; fn++) atomicAdd(&obuf[fn*16 + lr], s[fn]);
  }
  __syncthreads();
  if (tid < 64) out[ptile + tid] = obuf[tid] + bout[0];
}

extern "C" void kernel_launch(void* const* d_in, const int* in_sizes, int n_in,
                              void* d_out, int out_size, void* d_ws, size_t ws_size,
                              hipStream_t stream) {
  const float* p      = (const float*)d_in[0];
  const float* c_grid = (const float*)d_in[1];
  const float* c_xy   = (const float*)d_in[2];
  const float* c_yz   = (const float*)d_in[3];
  const float* c_xz   = (const float*)d_in[4];
  const float* Wp     = (const float*)d_in[5];
  const float* bp     = (const float*)d_in[6];
  const float* Wc     = (const float*)d_in[7];
  const float* bc     = (const float*)d_in[8];
  const float* W0     = (const float*)d_in[9];
  const float* b0     = (const float*)d_in[10];
  const float* W1     = (const float*)d_in[11];
  const float* b1     = (const float*)d_in[12];
  const float* Wout   = (const float*)d_in[13];
  const float* bout   = (const float*)d_in[14];

  char* ws = (char*)d_ws;
  unsigned short* wcp = (unsigned short*)(ws + OFF_WCP);
  unsigned short* w0p = (unsigned short*)(ws + OFF_W0P);
  unsigned short* w1p = (unsigned short*)(ws + OFF_W1P);
  unsigned short* gt  = (unsigned short*)(ws + OFF_GT);
  unsigned short* pt  = (unsigned short*)(ws + OFF_PT);
  float* out = (float*)d_out;

  prep<<<4480, 256, 0, stream>>>(Wc, W0, W1, c_grid, c_xy, c_yz, c_xz,
                                 wcp, w0p, w1p, gt, pt);
  mlp<<<MTOT / 64, 256, 0, stream>>>(p, Wp, bp, bc, b0, b1, Wout, bout,
                                     wcp, w0p, w1p, gt, pt, out);
}

// Round 16
// 490.790 us; speedup vs baseline: 1.1091x; 1.0058x over previous
//
#include <hip/hip_runtime.h>
#include <hip/hip_bf16.h>
#include <stdint.h>

#define BATCH 4
#define NPTS 50000
#define MTOT (BATCH * NPTS)   // 200000 points
#define HID 256
#define NBLK 5
#define CDIM 128

typedef float  floatx4 __attribute__((ext_vector_type(4)));
typedef short  short8  __attribute__((ext_vector_type(8)));

// ---- workspace layout (bytes) ----
#define OFF_WCP   0u           // 5*4*16*512 bf16  = 327,680 B
#define OFF_W0P   327680u      // 5*8*16*512 bf16  = 655,360 B
#define OFF_W1P   983040u      // 655,360 B
#define OFF_GT    1638400u     // 4*32768*32 bf16  = 8,388,608 B
#define OFF_PT    10027008u    // 3*4*16384*32 bf16 = 12,582,912 B  (end 22,609,920)

__device__ __forceinline__ unsigned short f2bf(float f) {
  unsigned u = __builtin_bit_cast(unsigned, f);
  u += 0x7fffu + ((u >> 16) & 1u);
  return (unsigned short)(u >> 16);
}
__device__ __forceinline__ unsigned pack2bf(float a, float b) {
  return (unsigned)f2bf(a) | ((unsigned)f2bf(b) << 16);
}
// packed cvt: lowers to v_cvt_pk_bf16_f32 on gfx950; RNE, value-identical to f2bf
__device__ __forceinline__ unsigned pk2(float a, float b) {
  __hip_bfloat162 t = __float22bfloat162_rn(make_float2(a, b));
  unsigned u; __builtin_memcpy(&u, &t, sizeof(u));
  return u;
}

// ---------------- prep: weight prepack + feature transpose (one launch) ----------------
// pack: fp32 row-major (K x 256) -> bf16 16x16x32 A-fragment-major.
// Fragment tile (ks, fm): 512 bf16, entry [l*8+j] = W[ks*32 + (l>>4)*8 + j][fm*16 + (l&15)]
__global__ void prep(const float* __restrict__ Wc, const float* __restrict__ W0,
                     const float* __restrict__ W1,
                     const float* __restrict__ g, const float* __restrict__ xy,
                     const float* __restrict__ yz, const float* __restrict__ xz,
                     unsigned short* __restrict__ wcp, unsigned short* __restrict__ w0p,
                     unsigned short* __restrict__ w1p,
                     unsigned short* __restrict__ gt, unsigned short* __restrict__ pt) {
  const int bid = blockIdx.x;
  if (bid < 3200) {
    // ---- weight pack: 819,200 elements ----
    int e = bid * 256 + threadIdx.x;
    const int WC_E = NBLK * 32768;   // 163840
    const int W_E  = NBLK * 65536;   // 327680
    const float* src;
    unsigned short* dst;
    int idx, per;
    if (e < WC_E)            { src = Wc; dst = wcp; idx = e;              per = 32768; }
    else if (e < WC_E + W_E) { src = W0; dst = w0p; idx = e - WC_E;       per = 65536; }
    else                     { src = W1; dst = w1p; idx = e - WC_E - W_E; per = 65536; }
    int blk = idx / per, r = idx % per;
    int j = r & 7, l = (r >> 3) & 63, tile = r >> 9;
    int fm = tile & 15, ks = tile >> 4;
    int k = ks * 32 + (l >> 4) * 8 + j;
    int n = fm * 16 + (l & 15);
    dst[idx] = f2bf(src[(size_t)blk * per + (size_t)k * 256 + n]);
    return;
  }
  // ---- feature transpose to channel-last bf16: 327,680 threads ----
  int tid = (bid - 3200) * 256 + threadIdx.x;
  float v[32];
  unsigned short* dst;
  if (tid < BATCH * 32768) {                 // grid: (B,32,32768) -> (B,32768,32)
    int b = tid >> 15, sp = tid & 32767;
    const float* src = g + ((size_t)b * 32) * 32768 + sp;
#pragma unroll
    for (int c = 0; c < 32; c++) v[c] = src[(size_t)c * 32768];
    dst = gt + (size_t)tid * 32;
  } else {                                   // planes: (3,B,32,16384) -> (3,B,16384,32)
    int t2 = tid - BATCH * 32768;
    int pl = t2 >> 16, rem = t2 & 65535;
    int b = rem >> 14, hw = rem & 16383;
    const float* pp = (pl == 0) ? xy : ((pl == 1) ? yz : xz);
    const float* src = pp + ((size_t)b * 32) * 16384 + hw;
#pragma unroll
    for (int c = 0; c < 32; c++) v[c] = src[(size_t)c * 16384];
    dst = pt + (size_t)t2 * 32;
  }
  uint4* d4 = (uint4*)dst;
#pragma unroll
  for (int i = 0; i < 4; i++) {
    uint4 u;
    u.x = pack2bf(v[i*8+0], v[i*8+1]);
    u.y = pack2bf(v[i*8+2], v[i*8+3]);
    u.z = pack2bf(v[i*8+4], v[i*8+5]);
    u.w = pack2bf(v[i*8+6], v[i*8+7]);
    d4[i] = u;
  }
}

// ---------------- interpolation helpers ----------
__device__ __forceinline__ void acc32(float* acc, const unsigned short* s, float w) {
  const uint4* q = (const uint4*)s;
#pragma unroll
  for (int i = 0; i < 4; i++) {
    uint4 u = q[i];
    acc[i*8+0] += w * __builtin_bit_cast(float, u.x << 16);
    acc[i*8+1] += w * __builtin_bit_cast(float, u.x & 0xffff0000u);
    acc[i*8+2] += w * __builtin_bit_cast(float, u.y << 16);
    acc[i*8+3] += w * __builtin_bit_cast(float, u.y & 0xffff0000u);
    acc[i*8+4] += w * __builtin_bit_cast(float, u.z << 16);
    acc[i*8+5] += w * __builtin_bit_cast(float, u.z & 0xffff0000u);
    acc[i*8+6] += w * __builtin_bit_cast(float, u.w << 16);
    acc[i*8+7] += w * __builtin_bit_cast(float, u.w & 0xffff0000u);
  }
}

// ---------------- fused gather + MLP ----------------
// R16 = R5 (verified twice: 417.5 / 415.1 us mlp) + ONE safe change:
//   S2's bias b0 folded into the MFMA accumulator INIT (D = A.B + C with C = b0)
//   instead of a post-hoc VALU add. Saves 64 wave-wide v_adds/iter and hoists the
//   b0 load off the store critical path (hidden under B1 wait + first MFMAs).
//   Pure per-thread reassociation: no barrier interaction, no load motion across
//   fences (the hazard class that sank R8/R14). bc/b1 cannot be folded (net
//   carries prior content).
// Everything else byte-identical to R5.
__global__ __launch_bounds__(256, 2) void mlp(
    const float* __restrict__ p, const float* __restrict__ Wp, const float* __restrict__ bp,
    const float* __restrict__ bc, const float* __restrict__ b0, const float* __restrict__ b1,
    const float* __restrict__ Wout, const float* __restrict__ bout,
    const unsigned short* __restrict__ wcp, const unsigned short* __restrict__ w0p,
    const unsigned short* __restrict__ w1p,
    const unsigned short* __restrict__ gt, const unsigned short* __restrict__ ptab,
    float* __restrict__ out) {
  __shared__ __align__(16) unsigned short smem[40960];   // 81,920 B exact
  char* actB  = (char*)smem;              // 64 rows x 512 B (swizzled)
  char* act2B = (char*)smem + 32768;      // 64 rows x 512 B (swizzled)
  char* cfLds = (char*)smem + 65536;      // 64 rows x 256 B (swizzled)
  float* obuf = (float*)((char*)smem + 65536);  // overlays cf; dead region at epilogue

  const int tid = threadIdx.x;
  const int w = tid >> 6, l = tid & 63, lq = l >> 4, lr = l & 15;
  const int rxl = (l & 7) << 4;           // swizzle term for row = *16 + lr accesses
  const int ptile = blockIdx.x * 64;

  // ---- gather prologue: 4 threads per point, one feature source each; stage into cf ----
  {
    int pl   = tid & 3;        // 0: grid, 1: xy, 2: yz, 3: xz
    int mloc = tid >> 2;       // 0..63
    int m = ptile + mloc;
    int b = m / NPTS;
    float px = p[3*m], py = p[3*m+1], pz = p[3*m+2];
    const float inv = 1.0f / 1.101f;       // 1/(1+PAD+1e-3)
    float ux = fminf(fmaxf(px * inv + 0.5f, 0.0f), 1.0f - 1e-5f);
    float uy = fminf(fmaxf(py * inv + 0.5f, 0.0f), 1.0f - 1e-5f);
    float uz = fminf(fmaxf(pz * inv + 0.5f, 0.0f), 1.0f - 1e-5f);
    float acc[32];
#pragma unroll
    for (int c = 0; c < 32; c++) acc[c] = 0.f;
    if (pl == 0) {
      // trilinear grid (x->W fastest), res 32
      float fx = ux * 31.f, fy = uy * 31.f, fz = uz * 31.f;
      int x0 = (int)fx, y0 = (int)fy, z0 = (int)fz;
      float wx = fx - x0, wy = fy - y0, wz = fz - z0;
      int x1 = min(x0 + 1, 31), y1 = min(y0 + 1, 31), z1 = min(z0 + 1, 31);
      const unsigned short* gb = gt + ((size_t)b * 32768) * 32;
      #define GI(z,y,x) (((size_t)(((z)*32 + (y))*32 + (x))) * 32)
      acc32(acc, gb + GI(z0,y0,x0), (1-wx)*(1-wy)*(1-wz));
      acc32(acc, gb + GI(z0,y0,x1), wx*(1-wy)*(1-wz));
      acc32(acc, gb + GI(z0,y1,x0), (1-wx)*wy*(1-wz));
      acc32(acc, gb + GI(z0,y1,x1), wx*wy*(1-wz));
      acc32(acc, gb + GI(z1,y0,x0), (1-wx)*(1-wy)*wz);
      acc32(acc, gb + GI(z1,y0,x1), wx*(1-wy)*wz);
      acc32(acc, gb + GI(z1,y1,x0), (1-wx)*wy*wz);
      acc32(acc, gb + GI(z1,y1,x1), wx*wy*wz);
    } else {
      // bilinear plane, res 128: xy(u=x,v=y), yz(u=y,v=z), xz(u=x,v=z)
      float uu = (pl == 2) ? uy : ux;
      float vv = (pl == 1) ? uy : uz;
      float fx = uu * 127.f, fy = vv * 127.f;
      int x0 = (int)fx, y0 = (int)fy;
      float wx = fx - x0, wy = fy - y0;
      int x1 = min(x0 + 1, 127), y1 = min(y0 + 1, 127);
      const unsigned short* pb = ptab + ((size_t)((pl - 1) * BATCH + b) * 16384) * 32;
      acc32(acc, pb + ((size_t)(y0*128 + x0)) * 32, (1-wx)*(1-wy));
      acc32(acc, pb + ((size_t)(y0*128 + x1)) * 32, wx*(1-wy));
      acc32(acc, pb + ((size_t)(y1*128 + x0)) * 32, (1-wx)*wy);
      acc32(acc, pb + ((size_t)(y1*128 + x1)) * 32, wx*wy);
    }
    // store 32 channels (bf16) to cf row mloc, byte cols pl*64 + i*16, swizzled
    int rxm = (mloc & 7) << 4;
    char* rowp = cfLds + mloc * 256;
#pragma unroll
    for (int i = 0; i < 4; i++) {
      uint4 u;
      u.x = pack2bf(acc[i*8+0], acc[i*8+1]);
      u.y = pack2bf(acc[i*8+2], acc[i*8+3]);
      u.z = pack2bf(acc[i*8+4], acc[i*8+5]);
      u.w = pack2bf(acc[i*8+6], acc[i*8+7]);
      *(uint4*)(rowp + ((pl*64 + i*16) ^ rxm)) = u;
    }
  }

  floatx4 net[4][4];   // [fm][fn]; hidden = w*64 + fm*16 + lq*4 + r ; point = fn*16 + lr

  // ---- init: net = p @ Wp + bp ----
  float pv[4][3];
#pragma unroll
  for (int fn = 0; fn < 4; fn++) {
    int pg = ptile + fn * 16 + lr;
    pv[fn][0] = p[pg*3]; pv[fn][1] = p[pg*3+1]; pv[fn][2] = p[pg*3+2];
  }
#pragma unroll
  for (int fm = 0; fm < 4; fm++) {
    int h4 = w*16 + fm*4 + lq;
    float4 w0q = ((const float4*)Wp)[h4];
    float4 w1q = ((const float4*)(Wp + 256))[h4];
    float4 w2q = ((const float4*)(Wp + 512))[h4];
    float4 bq  = ((const float4*)bp)[h4];
    float wq[4][3] = {{w0q.x,w1q.x,w2q.x},{w0q.y,w1q.y,w2q.y},
                      {w0q.z,w1q.z,w2q.z},{w0q.w,w1q.w,w2q.w}};
    float bb[4] = {bq.x, bq.y, bq.z, bq.w};
#pragma unroll
    for (int r = 0; r < 4; r++)
#pragma unroll
      for (int fn = 0; fn < 4; fn++)
        net[fm][fn][r] = bb[r] + pv[fn][0]*wq[r][0] + pv[fn][1]*wq[r][1] + pv[fn][2]*wq[r][2];
  }
  __syncthreads();   // cf staging complete (act/act2 untouched so far)

  for (int i = 0; i < NBLK; i++) {
    // ---- S1: net += Wc^T . c^T  (K = 128; B-frags re-read from cf LDS) ----
    const unsigned short* wcb = wcp + i * 32768;
#pragma unroll
    for (int ks = 0; ks < 4; ks++) {
      short8 af[4], bf[4];
#pragma unroll
      for (int fm = 0; fm < 4; fm++)
        af[fm] = *(const short8*)(wcb + (size_t)(ks*16 + w*4 + fm) * 512 + l*8);
#pragma unroll
      for (int fn = 0; fn < 4; fn++)
        bf[fn] = *(const short8*)(cfLds + (fn*16 + lr) * 256 + ((ks*64 + lq*16) ^ rxl));
      __builtin_amdgcn_s_setprio(1);
#pragma unroll
      for (int fm = 0; fm < 4; fm++)
#pragma unroll
        for (int fn = 0; fn < 4; fn++)
          net[fm][fn] = __builtin_amdgcn_mfma_f32_16x16x32_bf16(af[fm], bf[fn], net[fm][fn], 0, 0, 0);
      __builtin_amdgcn_s_setprio(0);
    }
    // ---- + bc, stage relu(net) -> act  (prev iter's S2 act-reads fenced by prev B2) ----
#pragma unroll
    for (int fm = 0; fm < 4; fm++) {
      float4 bq = ((const float4*)(bc + i*256))[w*16 + fm*4 + lq];
      float bb[4] = {bq.x, bq.y, bq.z, bq.w};
#pragma unroll
      for (int fn = 0; fn < 4; fn++) {
#pragma unroll
        for (int r = 0; r < 4; r++) net[fm][fn][r] += bb[r];
        uint2 uu;
        uu.x = pk2(fmaxf(net[fm][fn][0],0.f), fmaxf(net[fm][fn][1],0.f));
        uu.y = pk2(fmaxf(net[fm][fn][2],0.f), fmaxf(net[fm][fn][3],0.f));
        *(uint2*)(actB + (fn*16 + lr) * 512 + ((w*128 + fm*32 + lq*8) ^ rxl)) = uu;
      }
    }
    __syncthreads();   // B1: act complete; also fences last iter's act2 reads
    // ---- S2: h = W0^T . relu(net)^T + b0 (K = 256), UNSPLIT; b0 folded into C-init ----
    const unsigned short* w0b = w0p + i * 65536;
    floatx4 h[4][4];
#pragma unroll
    for (int fm = 0; fm < 4; fm++) {
      float4 bq = ((const float4*)(b0 + i*256))[w*16 + fm*4 + lq];
#pragma unroll
      for (int fn = 0; fn < 4; fn++)
        h[fm][fn] = (floatx4){bq.x, bq.y, bq.z, bq.w};
    }
#pragma unroll
    for (int ks = 0; ks < 8; ks++) {
      short8 af[4], bf[4];
#pragma unroll
      for (int fm = 0; fm < 4; fm++)
        af[fm] = *(const short8*)(w0b + (size_t)(ks*16 + w*4 + fm) * 512 + l*8);
#pragma unroll
      for (int fn = 0; fn < 4; fn++)
        bf[fn] = *(const short8*)(actB + (fn*16 + lr) * 512 + ((ks*64 + lq*16) ^ rxl));
      __builtin_amdgcn_s_setprio(1);
#pragma unroll
      for (int fm = 0; fm < 4; fm++)
#pragma unroll
        for (int fn = 0; fn < 4; fn++)
          h[fm][fn] = __builtin_amdgcn_mfma_f32_16x16x32_bf16(af[fm], bf[fn], h[fm][fn], 0, 0, 0);
      __builtin_amdgcn_s_setprio(0);
    }
#pragma unroll
    for (int fm = 0; fm < 4; fm++) {
#pragma unroll
      for (int fn = 0; fn < 4; fn++) {
        uint2 uu;
        uu.x = pk2(fmaxf(h[fm][fn][0],0.f), fmaxf(h[fm][fn][1],0.f));
        uu.y = pk2(fmaxf(h[fm][fn][2],0.f), fmaxf(h[fm][fn][3],0.f));
        *(uint2*)(act2B + (fn*16 + lr) * 512 + ((w*128 + fm*32 + lq*8) ^ rxl)) = uu;
      }
    }
    __syncthreads();   // B2: act2 complete; also fences this iter's act reads
    // ---- S3: net += W1^T . relu(h)^T + b1 ----
    const unsigned short* w1b = w1p + i * 65536;
#pragma unroll
    for (int ks = 0; ks < 8; ks++) {
      short8 af[4], bf[4];
#pragma unroll
      for (int fm = 0; fm < 4; fm++)
        af[fm] = *(const short8*)(w1b + (size_t)(ks*16 + w*4 + fm) * 512 + l*8);
#pragma unroll
      for (int fn = 0; fn < 4; fn++)
        bf[fn] = *(const short8*)(act2B + (fn*16 + lr) * 512 + ((ks*64 + lq*16) ^ rxl));
      __builtin_amdgcn_s_setprio(1);
#pragma unroll
      for (int fm = 0; fm < 4; fm++)
#pragma unroll
        for (int fn = 0; fn < 4; fn++)
          net[fm][fn] = __builtin_amdgcn_mfma_f32_16x16x32_bf16(af[fm], bf[fn], net[fm][fn], 0, 0, 0);
      __builtin_amdgcn_s_setprio(0);
    }
#pragma unroll
    for (int fm = 0; fm < 4; fm++) {
      float4 bq = ((const float4*)(b1 + i*256))[w*16 + fm*4 + lq];
      float bb[4] = {bq.x, bq.y, bq.z, bq.w};
#pragma unroll
      for (int r = 0; r < 4; r++)
#pragma unroll
        for (int fn = 0; fn < 4; fn++) net[fm][fn][r] += bb[r];
    }
  }

  // ---- out = relu(net) @ Wout + bout  (obuf overlays cf: cf reads ended pre-B1 of last iter) ----
  float s[4] = {0.f, 0.f, 0.f, 0.f};
#pragma unroll
  for (int fm = 0; fm < 4; fm++) {
    float4 wq = ((const float4*)Wout)[w*16 + fm*4 + lq];
    float wv[4] = {wq.x, wq.y, wq.z, wq.w};
#pragma unroll
    for (int r = 0; r < 4; r++)
#pragma unroll
      for (int fn = 0; fn < 4; fn++) s[fn] += fmaxf(net[fm][fn][r], 0.f) * wv[r];
  }
#pragma unroll
  for (int fn = 0; fn < 4; fn++) {
    s[fn] += __shfl_xor(s[fn], 16);
    s[fn] += __shfl_xor(s[fn], 32);
  }
  if (tid < 64) obuf[tid] = 0.f;
  __syncthreads();
  if (lq == 0) {
#pragma unroll
    for (int fn = 0; fn < 4; fn++) atomicAdd(&obuf[fn*16 + lr], s[fn]);
  }
  __syncthreads();
  if (tid < 64) out[ptile + tid] = obuf[tid] + bout[0];
}

extern "C" void kernel_launch(void* const* d_in, const int* in_sizes, int n_in,
                              void* d_out, int out_size, void* d_ws, size_t ws_size,
                              hipStream_t stream) {
  const float* p      = (const float*)d_in[0];
  const float* c_grid = (const float*)d_in[1];
  const float* c_xy   = (const float*)d_in[2];
  const float* c_yz   = (const float*)d_in[3];
  const float* c_xz   = (const float*)d_in[4];
  const float* Wp     = (const float*)d_in[5];
  const float* bp     = (const float*)d_in[6];
  const float* Wc     = (const float*)d_in[7];
  const float* bc     = (const float*)d_in[8];
  const float* W0     = (const float*)d_in[9];
  const float* b0     = (const float*)d_in[10];
  const float* W1     = (const float*)d_in[11];
  const float* b1     = (const float*)d_in[12];
  const float* Wout   = (const float*)d_in[13];
  const float* bout   = (const float*)d_in[14];

  char* ws = (char*)d_ws;
  unsigned short* wcp = (unsigned short*)(ws + OFF_WCP);
  unsigned short* w0p = (unsigned short*)(ws + OFF_W0P);
  unsigned short* w1p = (unsigned short*)(ws + OFF_W1P);
  unsigned short* gt  = (unsigned short*)(ws + OFF_GT);
  unsigned short* pt  = (unsigned short*)(ws + OFF_PT);
  float* out = (float*)d_out;

  prep<<<4480, 256, 0, stream>>>(Wc, W0, W1, c_grid, c_xy, c_yz, c_xz,
                                 wcp, w0p, w1p, gt, pt);
  mlp<<<MTOT / 64, 256, 0, stream>>>(p, Wp, bp, bc, b0, b1, Wout, bout,
                                     wcp, w0p, w1p, gt, pt, out);
}